// Round 3
// baseline (620.322 us; speedup 1.0000x reference)
//
#include <hip/hip_runtime.h>
#include <hip/hip_cooperative_groups.h>
#include <math.h>

namespace cg = cooperative_groups;

#define N_NODES 1000
#define E_EDGES 64000
#define GRID    256
#define BLOCK   512

typedef float fx4 __attribute__((ext_vector_type(4)));

struct Params {
  const float* x; const int* src; const int* dst;
  const float* W1; const float* b1;
  const float* W2; const float* b2;
  const float* W3; const float* b3;
  const float* Wd1; const float* bd1;
  const float* Wd2; const float* bd2;
  const float* Wd3; const float* bd3;
  const float* Wd4; const float* bd4;
  int* deg; int* row_ptr; int* cursor; int* csr; float* dinv;
  float* hs; float* hA; float* partial; float* y1; float* y2; float* y3;
  float* out;
};

union SM {
  int    sc[1024];
  float  xs[4][512];
  fx4    red4[512];
  float  red[512];
};

// ---- GEMM phase: hs[row][c] = dinv[row] * sum_k X[row][k] * W[k][c], 4 rows/block
template<int K>
__device__ void gemm_phase(const float* __restrict__ X, const float* __restrict__ W,
                           const float* __restrict__ dinv, float* __restrict__ hs,
                           int b, int t, SM& sm){
  float* xsf = (float*)sm.xs;
  if (b < 250){
    int row0 = b * 4;
    for (int idx = t; idx < 4 * K; idx += BLOCK){
      int r = idx >> (K == 128 ? 7 : 9);
      int k = idx & (K - 1);
      xsf[idx] = X[(row0 + r) * K + k];
    }
  }
  __syncthreads();
  if (b < 250){
    int row0 = b * 4;
    float a0 = 0.f, a1 = 0.f, a2 = 0.f, a3 = 0.f;
    #pragma unroll 4
    for (int k = 0; k < K; ++k){
      float w = W[k * 512 + t];
      a0 += xsf[0 * K + k] * w;
      a1 += xsf[1 * K + k] * w;
      a2 += xsf[2 * K + k] * w;
      a3 += xsf[3 * K + k] * w;
    }
    hs[(row0 + 0) * 512 + t] = a0 * dinv[row0 + 0];
    hs[(row0 + 1) * 512 + t] = a1 * dinv[row0 + 1];
    hs[(row0 + 2) * 512 + t] = a2 * dinv[row0 + 2];
    hs[(row0 + 3) * 512 + t] = a3 * dinv[row0 + 3];
  }
  __syncthreads();
}

// ---- AGG phase: out[n][f] = tanh(dinv[n]*sum_{e} hs[src_e][f] + bias[f]), 4 nodes/block
__device__ void agg_phase(const float* __restrict__ hs, const int* __restrict__ row_ptr,
                          const int* __restrict__ csr, const float* __restrict__ dinv,
                          const float* __restrict__ bias, float* __restrict__ outp,
                          int b, int t){
  if (b >= 250) return;
  int q  = t >> 7;           // node within block
  int f4 = t & 127;          // fx4 column
  int n  = b * 4 + q;
  int beg = row_ptr[n], end = row_ptr[n + 1];
  const fx4* h4 = (const fx4*)hs;
  fx4 s = {0.f, 0.f, 0.f, 0.f};
  int i = beg;
  for (; i + 4 <= end; i += 4){
    int s0 = csr[i], s1 = csr[i + 1], s2 = csr[i + 2], s3 = csr[i + 3];
    fx4 v0 = h4[s0 * 128 + f4], v1 = h4[s1 * 128 + f4];
    fx4 v2 = h4[s2 * 128 + f4], v3 = h4[s3 * 128 + f4];
    s += v0 + v1 + v2 + v3;
  }
  for (; i < end; ++i) s += h4[csr[i] * 128 + f4];
  float dn = dinv[n];
  fx4 bb = ((const fx4*)bias)[f4];
  fx4 o;
  o.x = tanhf(dn * s.x + bb.x);
  o.y = tanhf(dn * s.y + bb.y);
  o.z = tanhf(dn * s.z + bb.z);
  o.w = tanhf(dn * s.w + bb.w);
  ((fx4*)outp)[n * 128 + f4] = o;
}

__device__ inline float lrelu(float v){ return v > 0.f ? v : 0.1f * v; }

__global__ __launch_bounds__(BLOCK)
void k_all(Params p){
  cg::grid_group g = cg::this_grid();
  __shared__ SM sm;
  int b = blockIdx.x, t = threadIdx.x;
  int gt = b * BLOCK + t;

  // P0: deg = 1 (self loop)
  if (gt < N_NODES) p.deg[gt] = 1;
  g.sync();

  // P1: count edges by destination
  if (gt < E_EDGES) atomicAdd(&p.deg[p.dst[gt]], 1);
  g.sync();

  // P2: exclusive scan (block 0), row_ptr/cursor/self-loop/dinv
  if (b == 0){
    int* sc = sm.sc;
    sc[t]       = (t       < N_NODES) ? p.deg[t]       : 0;
    sc[t + 512] = (t + 512 < N_NODES) ? p.deg[t + 512] : 0;
    int off = 1;
    for (int d = 512; d > 0; d >>= 1){
      __syncthreads();
      if (t < d){
        int ai = off * (2 * t + 1) - 1;
        int bi = off * (2 * t + 2) - 1;
        sc[bi] += sc[ai];
      }
      off <<= 1;
    }
    __syncthreads();
    if (t == 0) sc[1023] = 0;
    for (int d = 1; d < 1024; d <<= 1){
      off >>= 1;
      __syncthreads();
      if (t < d){
        int ai = off * (2 * t + 1) - 1;
        int bi = off * (2 * t + 2) - 1;
        int tmp = sc[ai];
        sc[ai] = sc[bi];
        sc[bi] += tmp;
      }
    }
    __syncthreads();
    #pragma unroll
    for (int h = 0; h < 2; ++h){
      int i = t + h * 512;
      if (i < N_NODES){
        int excl = sc[i];
        p.row_ptr[i] = excl;
        p.cursor[i]  = excl + 1;          // slot 0 = self loop
        p.csr[excl]  = i;
        p.dinv[i]    = rsqrtf((float)p.deg[i]);
      }
    }
    if (t == 0) p.row_ptr[N_NODES] = E_EDGES + N_NODES;
    __syncthreads();
  }
  g.sync();

  // P3: CSR fill
  if (gt < E_EDGES){
    int pos = atomicAdd(&p.cursor[p.dst[gt]], 1);
    p.csr[pos] = p.src[gt];
  }
  g.sync();

  // ---- 3 GCN layers (hA holds activations; hs is scratch pre-agg) ----
  gemm_phase<128>(p.x,  p.W1, p.dinv, p.hs, b, t, sm);
  g.sync();
  agg_phase(p.hs, p.row_ptr, p.csr, p.dinv, p.b1, p.hA, b, t);
  g.sync();
  gemm_phase<512>(p.hA, p.W2, p.dinv, p.hs, b, t, sm);
  g.sync();
  agg_phase(p.hs, p.row_ptr, p.csr, p.dinv, p.b2, p.hA, b, t);
  g.sync();
  gemm_phase<512>(p.hA, p.W3, p.dinv, p.hs, b, t, sm);
  g.sync();
  agg_phase(p.hs, p.row_ptr, p.csr, p.dinv, p.b3, p.hA, b, t);
  g.sync();

  // ---- dense1: partial[b][j] over this block's 2000-row chunk of Wd1 ----
  {
    int r = t >> 6, c = t & 63;         // wave id, fx4 column
    int base = b * 2000;
    const fx4* W4 = (const fx4*)p.Wd1;
    const float*  f  = p.hA;
    fx4 acc = {0.f, 0.f, 0.f, 0.f};
    #pragma unroll 8
    for (int it = 0; it < 250; ++it){
      int i = base + it * 8 + r;
      float fv = f[i];
      fx4 w = __builtin_nontemporal_load(&W4[(size_t)i * 64 + c]);
      acc += fv * w;
    }
    sm.red4[t] = acc;
    __syncthreads();
    if (t < 256) sm.red4[t] += sm.red4[t + 256];
    __syncthreads();
    if (t < 128) sm.red4[t] += sm.red4[t + 128];
    __syncthreads();
    if (t < 64){
      fx4 a = sm.red4[t] + sm.red4[t + 64];
      ((fx4*)(p.partial + b * 256))[t] = a;
    }
  }
  g.sync();

  // ---- column reduce over 256 partials + bias + LeakyReLU -> y1 ----
  {
    float s = (t < 256) ? p.partial[t * 256 + b] : 0.f;
    sm.red[t] = s;
    __syncthreads();
    for (int off = 256; off > 0; off >>= 1){
      if (t < off) sm.red[t] += sm.red[t + off];
      __syncthreads();
    }
    if (t == 0) p.y1[b] = lrelu(sm.red[0] + p.bd1[b]);
  }
  g.sync();

  // ---- dense2 ----
  {
    float s = (t < 256) ? p.y1[t] * p.Wd2[t * 256 + b] : 0.f;
    sm.red[t] = s;
    __syncthreads();
    for (int off = 256; off > 0; off >>= 1){
      if (t < off) sm.red[t] += sm.red[t + off];
      __syncthreads();
    }
    if (t == 0) p.y2[b] = lrelu(sm.red[0] + p.bd2[b]);
  }
  g.sync();

  // ---- dense3 ----
  {
    float s = (t < 256) ? p.y2[t] * p.Wd3[t * 256 + b] : 0.f;
    sm.red[t] = s;
    __syncthreads();
    for (int off = 256; off > 0; off >>= 1){
      if (t < off) sm.red[t] += sm.red[t + off];
      __syncthreads();
    }
    if (t == 0) p.y3[b] = lrelu(sm.red[0] + p.bd3[b]);
  }
  g.sync();

  // ---- dense4: scalar output ----
  if (b == 0){
    float s = (t < 256) ? p.y3[t] * p.Wd4[t] : 0.f;
    sm.red[t] = s;
    __syncthreads();
    for (int off = 256; off > 0; off >>= 1){
      if (t < off) sm.red[t] += sm.red[t + off];
      __syncthreads();
    }
    if (t == 0) p.out[0] = sm.red[0] + p.bd4[0];
  }
}

extern "C" void kernel_launch(void* const* d_in, const int* in_sizes, int n_in,
                              void* d_out, int out_size, void* d_ws, size_t ws_size,
                              hipStream_t stream) {
  const int* ei = (const int*)d_in[1];
  char* ws = (char*)d_ws;

  Params p;
  p.x   = (const float*)d_in[0];
  p.src = ei;
  p.dst = ei + E_EDGES;
  p.W1  = (const float*)d_in[2];  p.b1  = (const float*)d_in[3];
  p.W2  = (const float*)d_in[4];  p.b2  = (const float*)d_in[5];
  p.W3  = (const float*)d_in[6];  p.b3  = (const float*)d_in[7];
  p.Wd1 = (const float*)d_in[8];  p.bd1 = (const float*)d_in[9];
  p.Wd2 = (const float*)d_in[10]; p.bd2 = (const float*)d_in[11];
  p.Wd3 = (const float*)d_in[12]; p.bd3 = (const float*)d_in[13];
  p.Wd4 = (const float*)d_in[14]; p.bd4 = (const float*)d_in[15];

  p.deg     = (int*)  (ws + 0);
  p.row_ptr = (int*)  (ws + 4096);
  p.cursor  = (int*)  (ws + 12288);
  p.dinv    = (float*)(ws + 16384);
  p.csr     = (int*)  (ws + 20480);                    // 65000 ints -> 260 KB
  p.hs      = (float*)(ws + 20480 + 262144);           // 2 MB
  p.hA      = (float*)(ws + 20480 + 262144 + 2097152); // 2 MB
  p.partial = (float*)(ws + 20480 + 262144 + 2*2097152);
  p.y1      = (float*)(ws + 20480 + 262144 + 2*2097152 + 262144);
  p.y2      = p.y1 + 256;
  p.y3      = p.y2 + 256;
  p.out     = (float*)d_out;

  void* args[] = { &p };
  (void)hipLaunchCooperativeKernel((void*)k_all, dim3(GRID), dim3(BLOCK), args, 0, stream);
}

// Round 4
// 359.222 us; speedup vs baseline: 1.7268x; 1.7268x over previous
//
#include <hip/hip_runtime.h>
#include <math.h>

#define N_NODES 1000
#define E_EDGES 64000
#define STRIDE  256   // padded CSR row stride (max degree ~110 for binomial(64000,1e-3))

typedef float fx4 __attribute__((ext_vector_type(4)));

__device__ inline float lrelu(float v){ return v > 0.f ? v : 0.1f * v; }

// ---- k0: padded-CSR build (blocks 0..124) + hs1 = x@W1 (unscaled, blocks 0..249)
__global__ __launch_bounds__(512)
void k0(const int* __restrict__ src, const int* __restrict__ dst,
        const float* __restrict__ x, const float* __restrict__ W1,
        int* __restrict__ cnt, int* __restrict__ csr, float* __restrict__ hs1){
  int b = blockIdx.x, t = threadIdx.x;
  if (b < 125){
    int e = b * 512 + t;                 // 125*512 == 64000 exactly
    int s = src[e], d = dst[e];
    int pos = atomicAdd(&cnt[d], 1);
    if (pos < STRIDE) csr[(d << 8) + pos] = s;
  }
  // GEMM: 4 rows/block, K=128, col = t
  __shared__ float xs[512];
  int row0 = b * 4;
  xs[t] = x[row0 * 128 + t];
  __syncthreads();
  float a0 = 0.f, a1 = 0.f, a2 = 0.f, a3 = 0.f;
  const fx4* xv = (const fx4*)xs;
  #pragma unroll 8
  for (int k4 = 0; k4 < 32; ++k4){
    fx4 h0 = xv[k4], h1 = xv[32 + k4], h2 = xv[64 + k4], h3 = xv[96 + k4];
    #pragma unroll
    for (int j = 0; j < 4; ++j){
      float w = W1[(k4 * 4 + j) * 512 + t];
      a0 += h0[j] * w; a1 += h1[j] * w; a2 += h2[j] * w; a3 += h3[j] * w;
    }
  }
  hs1[(row0 + 0) * 512 + t] = a0;
  hs1[(row0 + 1) * 512 + t] = a1;
  hs1[(row0 + 2) * 512 + t] = a2;
  hs1[(row0 + 3) * 512 + t] = a3;
}

// ---- k_layer: agg over hs_in (+bias,tanh) -> h (LDS) -> hs_out = dinv*(h@W)
// SCALE_SRC: layer-1 agg must apply dinv[src] per edge (hs1 unscaled);
// later layers read hs pre-scaled by dinv[src] at GEMM write time.
template<bool SCALE_SRC>
__global__ __launch_bounds__(512)
void k_layer(const float* __restrict__ hs_in, const int* __restrict__ cnt,
             const int* __restrict__ csr, const float* __restrict__ bias,
             const float* __restrict__ W, float* __restrict__ hs_out){
  __shared__ float dinv_lds[N_NODES];
  __shared__ float h_lds[4 * 512];
  int b = blockIdx.x, t = threadIdx.x;
  if (SCALE_SRC){
    for (int i = t; i < N_NODES; i += 512)
      dinv_lds[i] = rsqrtf((float)(cnt[i] + 1));
    __syncthreads();
  }
  int q  = t >> 7;            // node within block (128 threads/node)
  int f4 = t & 127;           // fx4 column
  int n  = b * 4 + q;
  int m  = cnt[n]; if (m > STRIDE) m = STRIDE;
  float dn = rsqrtf((float)(m + 1));
  const fx4* h4 = (const fx4*)hs_in;
  const int* row = csr + (n << 8);
  fx4 s = (SCALE_SRC ? dn : 1.f) * h4[n * 128 + f4];   // self loop
  int i = 0;
  for (; i + 4 <= m; i += 4){
    int4 s4 = *(const int4*)(row + i);
    if (SCALE_SRC){
      s += dinv_lds[s4.x] * h4[s4.x * 128 + f4];
      s += dinv_lds[s4.y] * h4[s4.y * 128 + f4];
      s += dinv_lds[s4.z] * h4[s4.z * 128 + f4];
      s += dinv_lds[s4.w] * h4[s4.w * 128 + f4];
    } else {
      s += h4[s4.x * 128 + f4] + h4[s4.y * 128 + f4]
         + h4[s4.z * 128 + f4] + h4[s4.w * 128 + f4];
    }
  }
  for (; i < m; ++i){
    int sv = row[i];
    s += (SCALE_SRC ? dinv_lds[sv] : 1.f) * h4[sv * 128 + f4];
  }
  fx4 bb = ((const fx4*)bias)[f4];
  fx4 o;
  o.x = tanhf(dn * s.x + bb.x);
  o.y = tanhf(dn * s.y + bb.y);
  o.z = tanhf(dn * s.z + bb.z);
  o.w = tanhf(dn * s.w + bb.w);
  ((fx4*)h_lds)[q * 128 + f4] = o;
  __syncthreads();
  // GEMM: col = t, 4 rows from LDS (wave-uniform fx4 broadcasts)
  float a0 = 0.f, a1 = 0.f, a2 = 0.f, a3 = 0.f;
  const fx4* hv = (const fx4*)h_lds;
  #pragma unroll 4
  for (int k4 = 0; k4 < 128; ++k4){
    fx4 h0 = hv[k4], h1 = hv[128 + k4], h2 = hv[256 + k4], h3 = hv[384 + k4];
    #pragma unroll
    for (int j = 0; j < 4; ++j){
      float w = W[(k4 * 4 + j) * 512 + t];
      a0 += h0[j] * w; a1 += h1[j] * w; a2 += h2[j] * w; a3 += h3[j] * w;
    }
  }
  int row0 = b * 4;
  float d0 = rsqrtf((float)(cnt[row0 + 0] + 1));
  float d1 = rsqrtf((float)(cnt[row0 + 1] + 1));
  float d2 = rsqrtf((float)(cnt[row0 + 2] + 1));
  float d3 = rsqrtf((float)(cnt[row0 + 3] + 1));
  hs_out[(row0 + 0) * 512 + t] = a0 * d0;
  hs_out[(row0 + 1) * 512 + t] = a1 * d1;
  hs_out[(row0 + 2) * 512 + t] = a2 * d2;
  hs_out[(row0 + 3) * 512 + t] = a3 * d3;
}

// ---- k_last: agg layer-3 -> f (LDS, rows b*2048..+2048) -> dense1 partial[b][256]
__global__ __launch_bounds__(512)
void k_last(const float* __restrict__ hs_in, const int* __restrict__ cnt,
            const int* __restrict__ csr, const float* __restrict__ bias,
            const float* __restrict__ Wd1, float* __restrict__ partial){
  __shared__ float f_lds[2048];
  __shared__ fx4 red4[512];
  int b = blockIdx.x, t = threadIdx.x;
  int q  = t >> 7;
  int f4 = t & 127;
  int n  = b * 4 + q;
  int m  = cnt[n]; if (m > STRIDE) m = STRIDE;
  float dn = rsqrtf((float)(m + 1));
  const fx4* h4 = (const fx4*)hs_in;
  const int* row = csr + (n << 8);
  fx4 s = h4[n * 128 + f4];                            // self (pre-scaled)
  int i = 0;
  for (; i + 4 <= m; i += 4){
    int4 s4 = *(const int4*)(row + i);
    s += h4[s4.x * 128 + f4] + h4[s4.y * 128 + f4]
       + h4[s4.z * 128 + f4] + h4[s4.w * 128 + f4];
  }
  for (; i < m; ++i) s += h4[row[i] * 128 + f4];
  fx4 bb = ((const fx4*)bias)[f4];
  fx4 o;
  o.x = tanhf(dn * s.x + bb.x);
  o.y = tanhf(dn * s.y + bb.y);
  o.z = tanhf(dn * s.z + bb.z);
  o.w = tanhf(dn * s.w + bb.w);
  ((fx4*)f_lds)[q * 128 + f4] = o;
  __syncthreads();
  // dense1: stream 2048 rows x 256 cols of Wd1; f broadcast from LDS
  int r = t >> 6, c = t & 63;          // 8 rows in flight, 64 fx4 cols
  const fx4* W4 = (const fx4*)Wd1 + (size_t)b * 131072 + c;
  fx4 acc = {0.f, 0.f, 0.f, 0.f};
  #pragma unroll 16
  for (int it = 0; it < 256; ++it){
    int i2 = it * 8 + r;
    acc += f_lds[i2] * W4[(size_t)i2 * 64];
  }
  red4[t] = acc;
  __syncthreads();
  if (t < 256) red4[t] += red4[t + 256];
  __syncthreads();
  if (t < 128) red4[t] += red4[t + 128];
  __syncthreads();
  if (t < 64)
    ((fx4*)(partial + b * 256))[t] = red4[t] + red4[t + 64];
}

// ---- k_tail: reduce partial(250x256)+bd1+lrelu -> d2 -> d3 -> d4, single block
__global__ __launch_bounds__(512)
void k_tail(const float* __restrict__ partial,
            const float* __restrict__ bd1,
            const float* __restrict__ Wd2, const float* __restrict__ bd2,
            const float* __restrict__ Wd3, const float* __restrict__ bd3,
            const float* __restrict__ Wd4, const float* __restrict__ bd4,
            float* __restrict__ out){
  __shared__ float sm[512];
  __shared__ float y[256];
  int t = threadIdx.x;
  int c = t & 255, h = t >> 8;
  // dense1 reduce
  float s = 0.f;
  for (int b = h * 125; b < h * 125 + 125; ++b) s += partial[b * 256 + c];
  sm[t] = s;
  __syncthreads();
  if (t < 256) y[t] = lrelu(sm[t] + sm[t + 256] + bd1[t]);
  __syncthreads();
  // dense2
  float a = 0.f;
  #pragma unroll 4
  for (int i = h * 128; i < h * 128 + 128; ++i) a += y[i] * Wd2[i * 256 + c];
  sm[t] = a;
  __syncthreads();
  if (t < 256) y[t] = lrelu(sm[t] + sm[t + 256] + bd2[t]);
  __syncthreads();
  // dense3
  a = 0.f;
  #pragma unroll 4
  for (int i = h * 128; i < h * 128 + 128; ++i) a += y[i] * Wd3[i * 256 + c];
  sm[t] = a;
  __syncthreads();
  if (t < 256) y[t] = lrelu(sm[t] + sm[t + 256] + bd3[t]);
  __syncthreads();
  // dense4
  sm[t] = (t < 256) ? y[t] * Wd4[t] : 0.f;
  __syncthreads();
  for (int off = 128; off > 0; off >>= 1){
    if (t < off) sm[t] += sm[t + off];
    __syncthreads();
  }
  if (t == 0) out[0] = sm[0] + bd4[0];
}

// ---------------- launch ----------------

extern "C" void kernel_launch(void* const* d_in, const int* in_sizes, int n_in,
                              void* d_out, int out_size, void* d_ws, size_t ws_size,
                              hipStream_t stream) {
  const float* x   = (const float*)d_in[0];
  const int*   ei  = (const int*)  d_in[1];
  const float* W1  = (const float*)d_in[2];  const float* b1  = (const float*)d_in[3];
  const float* W2  = (const float*)d_in[4];  const float* b2  = (const float*)d_in[5];
  const float* W3  = (const float*)d_in[6];  const float* b3  = (const float*)d_in[7];
  const float* Wd1 = (const float*)d_in[8];  const float* bd1 = (const float*)d_in[9];
  const float* Wd2 = (const float*)d_in[10]; const float* bd2 = (const float*)d_in[11];
  const float* Wd3 = (const float*)d_in[12]; const float* bd3 = (const float*)d_in[13];
  const float* Wd4 = (const float*)d_in[14]; const float* bd4 = (const float*)d_in[15];
  float* out = (float*)d_out;

  const int* src = ei;
  const int* dst = ei + E_EDGES;

  char* ws = (char*)d_ws;
  int*   cnt     = (int*)  (ws + 0);            // 4000 B
  int*   csr     = (int*)  (ws + 8192);         // 1000*256*4 = 1,024,000 B
  float* hsA     = (float*)(ws + 1114112);      // 2 MB
  float* hsB     = (float*)(ws + 1114112 + 2097152);
  float* partial = (float*)(ws + 1114112 + 2 * 2097152);  // 250*256*4

  (void)hipMemsetAsync(cnt, 0, N_NODES * sizeof(int), stream);
  k0<<<250, 512, 0, stream>>>(src, dst, x, W1, cnt, csr, hsA);
  k_layer<true ><<<250, 512, 0, stream>>>(hsA, cnt, csr, b1, W2, hsB);
  k_layer<false><<<250, 512, 0, stream>>>(hsB, cnt, csr, b2, W3, hsA);
  k_last<<<250, 512, 0, stream>>>(hsA, cnt, csr, b3, Wd1, partial);
  k_tail<<<1, 512, 0, stream>>>(partial, bd1, Wd2, bd2, Wd3, bd3, Wd4, bd4, out);
}

// Round 5
// 242.754 us; speedup vs baseline: 2.5554x; 1.4798x over previous
//
#include <hip/hip_runtime.h>
#include <math.h>

#define N_NODES 1000
#define E_EDGES 64000
#define STRIDE  256   // padded CSR row stride (max degree ~110 for this graph)

typedef float fx4 __attribute__((ext_vector_type(4)));
typedef float fx2 __attribute__((ext_vector_type(2)));

__device__ inline float lrelu(float v){ return v > 0.f ? v : 0.1f * v; }

// ---- k0: padded-CSR build (blocks 0..124) + hs1 = x@W1 (unscaled), 4 rows/block
__global__ __launch_bounds__(512)
void k0(const int* __restrict__ src, const int* __restrict__ dst,
        const float* __restrict__ x, const float* __restrict__ W1,
        int* __restrict__ cnt, int* __restrict__ csr, float* __restrict__ hs1){
  int b = blockIdx.x, t = threadIdx.x;
  if (b < 125){
    int e = b * 512 + t;                 // 125*512 == 64000 exactly
    int s = src[e], d = dst[e];
    int pos = atomicAdd(&cnt[d], 1);
    if (pos < STRIDE) csr[(d << 8) + pos] = s;
  }
  __shared__ float xs[512];
  int row0 = b * 4;
  xs[t] = x[row0 * 128 + t];
  __syncthreads();
  float a0 = 0.f, a1 = 0.f, a2 = 0.f, a3 = 0.f;
  const fx4* xv = (const fx4*)xs;
  #pragma unroll 8
  for (int k4 = 0; k4 < 32; ++k4){
    fx4 h0 = xv[k4], h1 = xv[32 + k4], h2 = xv[64 + k4], h3 = xv[96 + k4];
    #pragma unroll
    for (int j = 0; j < 4; ++j){
      float w = W1[(k4 * 4 + j) * 512 + t];
      a0 += h0[j] * w; a1 += h1[j] * w; a2 += h2[j] * w; a3 += h3[j] * w;
    }
  }
  hs1[(row0 + 0) * 512 + t] = a0;
  hs1[(row0 + 1) * 512 + t] = a1;
  hs1[(row0 + 2) * 512 + t] = a2;
  hs1[(row0 + 3) * 512 + t] = a3;
}

// ---- k_layer: agg(+bias,tanh) -> h_lds -> hs_out = dinv_dst*(h@W) (pre-scaled for next agg)
template<bool SCALE_SRC>
__global__ __launch_bounds__(1024)
void k_layer(const float* __restrict__ hs_in, const int* __restrict__ cnt,
             const int* __restrict__ csr, const float* __restrict__ bias,
             const float* __restrict__ W, float* __restrict__ hs_out){
  __shared__ float dinv_lds[N_NODES];
  __shared__ float h_lds[4 * 512];
  int b = blockIdx.x, t = threadIdx.x;
  if (SCALE_SRC){
    if (t < N_NODES) dinv_lds[t] = rsqrtf((float)(cnt[t] + 1));
    __syncthreads();
  }
  // ---- agg: 4 nodes x 256 threads, fx2 per thread ----
  int q = t >> 8, tt = t & 255;
  int n = b * 4 + q;
  int m = cnt[n]; if (m > STRIDE) m = STRIDE;
  float dn = rsqrtf((float)(m + 1));
  const fx2* h2 = (const fx2*)hs_in;
  const int* row = csr + (n << 8);
  fx2 s = (SCALE_SRC ? dn : 1.f) * h2[n * 256 + tt];   // self loop
  int i = 0;
  for (; i + 4 <= m; i += 4){
    int4 s4 = *(const int4*)(row + i);
    if (SCALE_SRC){
      s += dinv_lds[s4.x] * h2[s4.x * 256 + tt];
      s += dinv_lds[s4.y] * h2[s4.y * 256 + tt];
      s += dinv_lds[s4.z] * h2[s4.z * 256 + tt];
      s += dinv_lds[s4.w] * h2[s4.w * 256 + tt];
    } else {
      s += h2[s4.x * 256 + tt] + h2[s4.y * 256 + tt]
         + h2[s4.z * 256 + tt] + h2[s4.w * 256 + tt];
    }
  }
  for (; i < m; ++i){
    int sv = row[i];
    s += (SCALE_SRC ? dinv_lds[sv] : 1.f) * h2[sv * 256 + tt];
  }
  fx2 bb = ((const fx2*)bias)[tt];
  fx2 o;
  o.x = tanhf(dn * s.x + bb.x);
  o.y = tanhf(dn * s.y + bb.y);
  ((fx2*)h_lds)[q * 256 + tt] = o;
  __syncthreads();
  // ---- GEMM: col = t&511, 2 rows per thread, h broadcast from LDS ----
  int col = t & 511, rh = t >> 9;
  float a0 = 0.f, a1 = 0.f;
  const fx4* hv = (const fx4*)h_lds;
  #pragma unroll 4
  for (int k4 = 0; k4 < 128; ++k4){
    fx4 h0 = hv[(rh * 2 + 0) * 128 + k4];
    fx4 h1 = hv[(rh * 2 + 1) * 128 + k4];
    #pragma unroll
    for (int j = 0; j < 4; ++j){
      float w = W[(k4 * 4 + j) * 512 + col];
      a0 += h0[j] * w; a1 += h1[j] * w;
    }
  }
  int r0 = b * 4 + rh * 2;
  hs_out[(r0 + 0) * 512 + col] = a0 * rsqrtf((float)(cnt[r0 + 0] + 1));
  hs_out[(r0 + 1) * 512 + col] = a1 * rsqrtf((float)(cnt[r0 + 1] + 1));
}

// ---- k_last: agg layer-3 -> f_lds -> NT-stream Wd1 chunk -> partial; last block does tail
__global__ __launch_bounds__(1024)
void k_last(const float* __restrict__ hs_in, const int* __restrict__ cnt,
            const int* __restrict__ csr, const float* __restrict__ bias,
            const float* __restrict__ Wd1, float* __restrict__ partial,
            int* __restrict__ done,
            const float* __restrict__ bd1,
            const float* __restrict__ Wd2, const float* __restrict__ bd2,
            const float* __restrict__ Wd3, const float* __restrict__ bd3,
            const float* __restrict__ Wd4, const float* __restrict__ bd4,
            float* __restrict__ out){
  __shared__ float f_lds[2048];
  __shared__ fx4 red4[1024];
  __shared__ float y[256];
  __shared__ int flag;
  int b = blockIdx.x, t = threadIdx.x;
  // ---- agg (inputs pre-scaled by dinv[src]) ----
  int q = t >> 8, tt = t & 255;
  int n = b * 4 + q;
  int m = cnt[n]; if (m > STRIDE) m = STRIDE;
  float dn = rsqrtf((float)(m + 1));
  const fx2* h2 = (const fx2*)hs_in;
  const int* row = csr + (n << 8);
  fx2 s = h2[n * 256 + tt];
  int i = 0;
  for (; i + 4 <= m; i += 4){
    int4 s4 = *(const int4*)(row + i);
    s += h2[s4.x * 256 + tt] + h2[s4.y * 256 + tt]
       + h2[s4.z * 256 + tt] + h2[s4.w * 256 + tt];
  }
  for (; i < m; ++i) s += h2[row[i] * 256 + tt];
  fx2 bb = ((const fx2*)bias)[tt];
  fx2 o;
  o.x = tanhf(dn * s.x + bb.x);
  o.y = tanhf(dn * s.y + bb.y);
  ((fx2*)f_lds)[q * 256 + tt] = o;
  __syncthreads();
  // ---- dense1: NT-stream 2048 rows x 256 cols of Wd1 ----
  int r = t >> 6, c = t & 63;          // 16 rows in flight, 64 fx4 cols
  const fx4* W4 = (const fx4*)Wd1 + (size_t)b * 131072 + c;
  fx4 acc = {0.f, 0.f, 0.f, 0.f};
  #pragma unroll 8
  for (int it = 0; it < 128; ++it){
    int i2 = it * 16 + r;
    acc += f_lds[i2] * __builtin_nontemporal_load(&W4[(size_t)i2 * 64]);
  }
  red4[t] = acc;
  __syncthreads();
  if (t < 512) red4[t] += red4[t + 512];
  __syncthreads();
  if (t < 256) red4[t] += red4[t + 256];
  __syncthreads();
  if (t < 128) red4[t] += red4[t + 128];
  __syncthreads();
  if (t < 64) ((fx4*)(partial + b * 256))[t] = red4[t] + red4[t + 64];
  __syncthreads();
  // ---- last-block-done: only the final block runs the dense tail ----
  if (t == 0){
    __threadfence();                   // release: flush partial to device scope
    int old = atomicAdd(done, 1);
    flag = (old == 249);
  }
  __syncthreads();
  if (!flag) return;
  __threadfence();                     // acquire: invalidate stale lines
  float* sm = (float*)red4;            // reuse 4KB of red4
  int c2 = t & 255, h = t >> 8;
  // dense1 reduce + bias + lrelu
  float sum = 0.f;
  for (int bb2 = h; bb2 < 250; bb2 += 4) sum += partial[bb2 * 256 + c2];
  sm[t] = sum;
  __syncthreads();
  if (t < 512) sm[t] += sm[t + 512];
  __syncthreads();
  if (t < 256) y[t] = lrelu(sm[t] + sm[t + 256] + bd1[t]);
  __syncthreads();
  // dense2
  float a = 0.f;
  #pragma unroll 4
  for (int i3 = h * 64; i3 < h * 64 + 64; ++i3) a += y[i3] * Wd2[i3 * 256 + c2];
  sm[t] = a;
  __syncthreads();
  if (t < 512) sm[t] += sm[t + 512];
  __syncthreads();
  if (t < 256) y[t] = lrelu(sm[t] + sm[t + 256] + bd2[t]);
  __syncthreads();
  // dense3
  a = 0.f;
  #pragma unroll 4
  for (int i3 = h * 64; i3 < h * 64 + 64; ++i3) a += y[i3] * Wd3[i3 * 256 + c2];
  sm[t] = a;
  __syncthreads();
  if (t < 512) sm[t] += sm[t + 512];
  __syncthreads();
  if (t < 256) y[t] = lrelu(sm[t] + sm[t + 256] + bd3[t]);
  __syncthreads();
  // dense4
  sm[t] = (t < 256) ? y[t] * Wd4[t] : 0.f;
  __syncthreads();
  for (int off = 128; off > 0; off >>= 1){
    if (t < off) sm[t] += sm[t + off];
    __syncthreads();
  }
  if (t == 0) out[0] = sm[0] + bd4[0];
}

// ---------------- launch ----------------

extern "C" void kernel_launch(void* const* d_in, const int* in_sizes, int n_in,
                              void* d_out, int out_size, void* d_ws, size_t ws_size,
                              hipStream_t stream) {
  const float* x   = (const float*)d_in[0];
  const int*   ei  = (const int*)  d_in[1];
  const float* W1  = (const float*)d_in[2];  const float* b1  = (const float*)d_in[3];
  const float* W2  = (const float*)d_in[4];  const float* b2  = (const float*)d_in[5];
  const float* W3  = (const float*)d_in[6];  const float* b3  = (const float*)d_in[7];
  const float* Wd1 = (const float*)d_in[8];  const float* bd1 = (const float*)d_in[9];
  const float* Wd2 = (const float*)d_in[10]; const float* bd2 = (const float*)d_in[11];
  const float* Wd3 = (const float*)d_in[12]; const float* bd3 = (const float*)d_in[13];
  const float* Wd4 = (const float*)d_in[14]; const float* bd4 = (const float*)d_in[15];
  float* out = (float*)d_out;

  const int* src = ei;
  const int* dst = ei + E_EDGES;

  char* ws = (char*)d_ws;
  int*   cnt     = (int*)  (ws + 0);            // 4000 B
  int*   done    = (int*)  (ws + 4096);
  int*   csr     = (int*)  (ws + 8192);         // 1000*256*4 = 1,024,000 B
  float* hsA     = (float*)(ws + 1114112);      // 2 MB
  float* hsB     = (float*)(ws + 1114112 + 2097152);
  float* partial = (float*)(ws + 1114112 + 2 * 2097152);  // 250*256*4

  (void)hipMemsetAsync(ws, 0, 8192, stream);    // cnt + done
  k0<<<250, 512, 0, stream>>>(src, dst, x, W1, cnt, csr, hsA);
  k_layer<true ><<<250, 1024, 0, stream>>>(hsA, cnt, csr, b1, W2, hsB);
  k_layer<false><<<250, 1024, 0, stream>>>(hsB, cnt, csr, b2, W3, hsA);
  k_last<<<250, 1024, 0, stream>>>(hsA, cnt, csr, b3, Wd1, partial, done,
                                   bd1, Wd2, bd2, Wd3, bd3, Wd4, bd4, out);
}

// Round 6
// 220.791 us; speedup vs baseline: 2.8095x; 1.0995x over previous
//
#include <hip/hip_runtime.h>
#include <math.h>

#define N_NODES 1000
#define E_EDGES 64000
#define STRIDE  256   // padded CSR row stride (max degree ~110 for this graph)

typedef float fx4 __attribute__((ext_vector_type(4)));
typedef float fx2 __attribute__((ext_vector_type(2)));

__device__ inline float lrelu(float v){ return v > 0.f ? v : 0.1f * v; }

// ---- k0: padded-CSR build only
__global__ __launch_bounds__(512)
void k0(const int* __restrict__ src, const int* __restrict__ dst,
        int* __restrict__ cnt, int* __restrict__ csr){
  int e = blockIdx.x * 512 + threadIdx.x;       // 125*512 == 64000 exactly
  int s = src[e], d = dst[e];
  int pos = atomicAdd(&cnt[d], 1);
  if (pos < STRIDE) csr[(d << 8) + pos] = s;
}

// ---- kA: agg(x) [128-wide] -> GEMM1+b1+tanh -> GEMM2 -> hs2 = dinv (.) (h1@W2)
__global__ __launch_bounds__(1024)
void kA(const float* __restrict__ x, const int* __restrict__ cnt,
        const int* __restrict__ csr, const float* __restrict__ W1,
        const float* __restrict__ b1, const float* __restrict__ W2,
        float* __restrict__ hs2){
  __shared__ float dinv_lds[1024];
  __shared__ fx4 gsum[4][8][32];     // 16 KB gather partials
  __shared__ float xa[4 * 128];      // aggregated x rows
  __shared__ float h1[4 * 512];      // tanh layer-1 output
  __shared__ float gpart[4 * 512];   // k-split reduce buffer
  int b = blockIdx.x, t = threadIdx.x;
  if (t < N_NODES) dinv_lds[t] = rsqrtf((float)(cnt[t] + 1));
  __syncthreads();
  // gather x: node q (4/block), 256 threads/node: fx4 col c (32), slice sl (8)
  int q = t >> 8, tt = t & 255;
  int c = tt & 31, sl = tt >> 5;
  int n = b * 4 + q;
  int m = cnt[n]; if (m > STRIDE) m = STRIDE;
  const fx4* x4 = (const fx4*)x;
  const int* row = csr + (n << 8);
  fx4 acc = {0.f, 0.f, 0.f, 0.f};
  if (sl == 0) acc = dinv_lds[n] * x4[n * 32 + c];     // self loop
  for (int i = sl; i < m; i += 8){
    int sv = row[i];
    acc += dinv_lds[sv] * x4[sv * 32 + c];
  }
  gsum[q][sl][c] = acc;
  __syncthreads();
  if (sl < 4) gsum[q][sl][c] += gsum[q][sl + 4][c];
  __syncthreads();
  if (sl < 2) gsum[q][sl][c] += gsum[q][sl + 2][c];
  __syncthreads();
  if (sl == 0)
    ((fx4*)xa)[q * 32 + c] = dinv_lds[n] * (gsum[q][0][c] + gsum[q][1][c]);
  __syncthreads();
  // GEMM1: [4x128]@[128x512] + b1, tanh -> h1 (k-split: W1 read once/block)
  int col = t & 511, kh = t >> 9;
  {
    float a0 = 0.f, a1 = 0.f, a2 = 0.f, a3 = 0.f;
    int kbeg = kh * 64;
    #pragma unroll 8
    for (int k = kbeg; k < kbeg + 64; ++k){
      float w = W1[k * 512 + col];
      a0 += xa[0 * 128 + k] * w; a1 += xa[1 * 128 + k] * w;
      a2 += xa[2 * 128 + k] * w; a3 += xa[3 * 128 + k] * w;
    }
    if (kh == 1){
      gpart[0 * 512 + col] = a0; gpart[1 * 512 + col] = a1;
      gpart[2 * 512 + col] = a2; gpart[3 * 512 + col] = a3;
    }
    __syncthreads();
    if (kh == 0){
      float bb = b1[col];
      h1[0 * 512 + col] = tanhf(a0 + gpart[0 * 512 + col] + bb);
      h1[1 * 512 + col] = tanhf(a1 + gpart[1 * 512 + col] + bb);
      h1[2 * 512 + col] = tanhf(a2 + gpart[2 * 512 + col] + bb);
      h1[3 * 512 + col] = tanhf(a3 + gpart[3 * 512 + col] + bb);
    }
    __syncthreads();
  }
  // GEMM2: [4x512]@[512x512] -> hs2, pre-scaled by dinv_dst (k-split)
  {
    float a0 = 0.f, a1 = 0.f, a2 = 0.f, a3 = 0.f;
    int kbeg = kh * 256;
    #pragma unroll 4
    for (int k = kbeg; k < kbeg + 256; ++k){
      float w = W2[k * 512 + col];
      a0 += h1[0 * 512 + k] * w; a1 += h1[1 * 512 + k] * w;
      a2 += h1[2 * 512 + k] * w; a3 += h1[3 * 512 + k] * w;
    }
    if (kh == 1){
      gpart[0 * 512 + col] = a0; gpart[1 * 512 + col] = a1;
      gpart[2 * 512 + col] = a2; gpart[3 * 512 + col] = a3;
    }
    __syncthreads();
    if (kh == 0){
      int r0 = b * 4;
      hs2[(size_t)(r0 + 0) * 512 + col] = (a0 + gpart[0 * 512 + col]) * dinv_lds[r0 + 0];
      hs2[(size_t)(r0 + 1) * 512 + col] = (a1 + gpart[1 * 512 + col]) * dinv_lds[r0 + 1];
      hs2[(size_t)(r0 + 2) * 512 + col] = (a2 + gpart[2 * 512 + col]) * dinv_lds[r0 + 2];
      hs2[(size_t)(r0 + 3) * 512 + col] = (a3 + gpart[3 * 512 + col]) * dinv_lds[r0 + 3];
    }
  }
}

// ---- kB: agg(hs_in pre-scaled) + b,tanh -> GEMM W3 (k-split) -> hs_out pre-scaled
__global__ __launch_bounds__(1024)
void kB(const float* __restrict__ hs_in, const int* __restrict__ cnt,
        const int* __restrict__ csr, const float* __restrict__ bias,
        const float* __restrict__ W, float* __restrict__ hs_out){
  __shared__ float h2l[4 * 512];
  __shared__ float gpart[4 * 512];
  __shared__ fx4 hpart[4][128];
  int b = blockIdx.x, t = threadIdx.x;
  int q = t >> 8, tt = t & 255;
  int c = tt & 127, half = tt >> 7;
  int n = b * 4 + q;
  int m = cnt[n]; if (m > STRIDE) m = STRIDE;
  const fx4* h4 = (const fx4*)hs_in;
  const int* row = csr + (n << 8);
  fx4 s = {0.f, 0.f, 0.f, 0.f};
  if (half == 0) s = h4[n * 128 + c];            // self (pre-scaled)
  int i = half;
  for (; i + 6 < m; i += 8){
    int s0 = row[i], s1 = row[i + 2], s2 = row[i + 4], s3 = row[i + 6];
    s += h4[s0 * 128 + c] + h4[s1 * 128 + c]
       + h4[s2 * 128 + c] + h4[s3 * 128 + c];
  }
  for (; i < m; i += 2) s += h4[row[i] * 128 + c];
  if (half == 1) hpart[q][c] = s;
  __syncthreads();
  if (half == 0){
    s += hpart[q][c];
    float dn = rsqrtf((float)(m + 1));
    fx4 bb = ((const fx4*)bias)[c];
    fx4 o;
    o.x = tanhf(dn * s.x + bb.x);
    o.y = tanhf(dn * s.y + bb.y);
    o.z = tanhf(dn * s.z + bb.z);
    o.w = tanhf(dn * s.w + bb.w);
    ((fx4*)h2l)[q * 128 + c] = o;
  }
  __syncthreads();
  // GEMM: [4x512]@[512x512], k-split, W read once/block
  int col = t & 511, kh = t >> 9;
  float a0 = 0.f, a1 = 0.f, a2 = 0.f, a3 = 0.f;
  int kbeg = kh * 256;
  #pragma unroll 4
  for (int k = kbeg; k < kbeg + 256; ++k){
    float w = W[k * 512 + col];
    a0 += h2l[0 * 512 + k] * w; a1 += h2l[1 * 512 + k] * w;
    a2 += h2l[2 * 512 + k] * w; a3 += h2l[3 * 512 + k] * w;
  }
  if (kh == 1){
    gpart[0 * 512 + col] = a0; gpart[1 * 512 + col] = a1;
    gpart[2 * 512 + col] = a2; gpart[3 * 512 + col] = a3;
  }
  __syncthreads();
  if (kh == 0){
    int r0 = b * 4;
    hs_out[(size_t)(r0 + 0) * 512 + col] = (a0 + gpart[0 * 512 + col]) * rsqrtf((float)(cnt[r0 + 0] + 1));
    hs_out[(size_t)(r0 + 1) * 512 + col] = (a1 + gpart[1 * 512 + col]) * rsqrtf((float)(cnt[r0 + 1] + 1));
    hs_out[(size_t)(r0 + 2) * 512 + col] = (a2 + gpart[2 * 512 + col]) * rsqrtf((float)(cnt[r0 + 2] + 1));
    hs_out[(size_t)(r0 + 3) * 512 + col] = (a3 + gpart[3 * 512 + col]) * rsqrtf((float)(cnt[r0 + 3] + 1));
  }
}

// ---- kC: agg layer-3 -> f_lds -> NT-stream Wd1 chunk -> partial; last block tail
__global__ __launch_bounds__(1024)
void kC(const float* __restrict__ hs_in, const int* __restrict__ cnt,
        const int* __restrict__ csr, const float* __restrict__ bias,
        const float* __restrict__ Wd1, float* __restrict__ partial,
        int* __restrict__ done,
        const float* __restrict__ bd1,
        const float* __restrict__ Wd2, const float* __restrict__ bd2,
        const float* __restrict__ Wd3, const float* __restrict__ bd3,
        const float* __restrict__ Wd4, const float* __restrict__ bd4,
        float* __restrict__ out){
  __shared__ float f_lds[2048];
  __shared__ fx4 red4[1024];
  __shared__ float y[256];
  __shared__ int flag;
  int b = blockIdx.x, t = threadIdx.x;
  // warm-touch Wd2/Wd3 into L2/L3 (they get evicted by the Wd1 stream)
  if (b < 8){
    const fx4* w2 = (const fx4*)Wd2;
    const fx4* w3 = (const fx4*)Wd3;
    fx4 v0 = w2[b * 2048 + t] + w3[b * 2048 + t];
    fx4 v1 = w2[b * 2048 + 1024 + t] + w3[b * 2048 + 1024 + t];
    float dm = v0.x + v1.x;
    asm volatile("" :: "v"(dm));
  }
  // ---- agg (inputs pre-scaled by dinv[src]) ----
  int q = t >> 8, tt = t & 255;
  int n = b * 4 + q;
  int m = cnt[n]; if (m > STRIDE) m = STRIDE;
  float dn = rsqrtf((float)(m + 1));
  const fx2* h2 = (const fx2*)hs_in;
  const int* row = csr + (n << 8);
  fx2 s = h2[n * 256 + tt];
  int i = 0;
  for (; i + 4 <= m; i += 4){
    int4 s4 = *(const int4*)(row + i);
    s += h2[s4.x * 256 + tt] + h2[s4.y * 256 + tt]
       + h2[s4.z * 256 + tt] + h2[s4.w * 256 + tt];
  }
  for (; i < m; ++i) s += h2[row[i] * 256 + tt];
  fx2 bb = ((const fx2*)bias)[tt];
  fx2 o;
  o.x = tanhf(dn * s.x + bb.x);
  o.y = tanhf(dn * s.y + bb.y);
  ((fx2*)f_lds)[q * 256 + tt] = o;
  __syncthreads();
  // ---- dense1: NT-stream 2048 rows x 256 cols of Wd1 ----
  int r = t >> 6, c = t & 63;          // 16 rows in flight, 64 fx4 cols
  const fx4* W4 = (const fx4*)Wd1 + (size_t)b * 131072 + c;
  fx4 acc = {0.f, 0.f, 0.f, 0.f};
  #pragma unroll 8
  for (int it = 0; it < 128; ++it){
    int i2 = it * 16 + r;
    acc += f_lds[i2] * __builtin_nontemporal_load(&W4[(size_t)i2 * 64]);
  }
  red4[t] = acc;
  __syncthreads();
  if (t < 512) red4[t] += red4[t + 512];
  __syncthreads();
  if (t < 256) red4[t] += red4[t + 256];
  __syncthreads();
  if (t < 128) red4[t] += red4[t + 128];
  __syncthreads();
  if (t < 64) ((fx4*)(partial + b * 256))[t] = red4[t] + red4[t + 64];
  __syncthreads();
  // ---- last-block-done: only the final block runs the dense tail ----
  if (t == 0){
    __threadfence();
    int old = atomicAdd(done, 1);
    flag = (old == 249);
  }
  __syncthreads();
  if (!flag) return;
  __threadfence();
  float* sm = (float*)red4;
  int c2 = t & 255, h = t >> 8;
  // dense1 reduce + bias + lrelu
  float sum = 0.f;
  for (int bb2 = h; bb2 < 250; bb2 += 4) sum += partial[bb2 * 256 + c2];
  sm[t] = sum;
  __syncthreads();
  if (t < 512) sm[t] += sm[t + 512];
  __syncthreads();
  if (t < 256) y[t] = lrelu(sm[t] + sm[t + 256] + bd1[t]);
  __syncthreads();
  // dense2
  float a = 0.f;
  #pragma unroll 4
  for (int i3 = h * 64; i3 < h * 64 + 64; ++i3) a += y[i3] * Wd2[i3 * 256 + c2];
  sm[t] = a;
  __syncthreads();
  if (t < 512) sm[t] += sm[t + 512];
  __syncthreads();
  if (t < 256) y[t] = lrelu(sm[t] + sm[t + 256] + bd2[t]);
  __syncthreads();
  // dense3
  a = 0.f;
  #pragma unroll 4
  for (int i3 = h * 64; i3 < h * 64 + 64; ++i3) a += y[i3] * Wd3[i3 * 256 + c2];
  sm[t] = a;
  __syncthreads();
  if (t < 512) sm[t] += sm[t + 512];
  __syncthreads();
  if (t < 256) y[t] = lrelu(sm[t] + sm[t + 256] + bd3[t]);
  __syncthreads();
  // dense4
  sm[t] = (t < 256) ? y[t] * Wd4[t] : 0.f;
  __syncthreads();
  for (int off = 128; off > 0; off >>= 1){
    if (t < off) sm[t] += sm[t + off];
    __syncthreads();
  }
  if (t == 0) out[0] = sm[0] + bd4[0];
}

// ---------------- launch ----------------

extern "C" void kernel_launch(void* const* d_in, const int* in_sizes, int n_in,
                              void* d_out, int out_size, void* d_ws, size_t ws_size,
                              hipStream_t stream) {
  const float* x   = (const float*)d_in[0];
  const int*   ei  = (const int*)  d_in[1];
  const float* W1  = (const float*)d_in[2];  const float* b1  = (const float*)d_in[3];
  const float* W2  = (const float*)d_in[4];  const float* b2  = (const float*)d_in[5];
  const float* W3  = (const float*)d_in[6];  const float* b3  = (const float*)d_in[7];
  const float* Wd1 = (const float*)d_in[8];  const float* bd1 = (const float*)d_in[9];
  const float* Wd2 = (const float*)d_in[10]; const float* bd2 = (const float*)d_in[11];
  const float* Wd3 = (const float*)d_in[12]; const float* bd3 = (const float*)d_in[13];
  const float* Wd4 = (const float*)d_in[14]; const float* bd4 = (const float*)d_in[15];
  float* out = (float*)d_out;

  const int* src = ei;
  const int* dst = ei + E_EDGES;

  char* ws = (char*)d_ws;
  int*   cnt     = (int*)  (ws + 0);
  int*   done    = (int*)  (ws + 4096);
  int*   csr     = (int*)  (ws + 8192);                   // 1000*256*4 B
  float* hsA     = (float*)(ws + 1114112);                // 2 MB
  float* hsB     = (float*)(ws + 1114112 + 2097152);      // 2 MB
  float* partial = (float*)(ws + 1114112 + 2 * 2097152);  // 250*256*4

  (void)hipMemsetAsync(ws, 0, 8192, stream);              // cnt + done
  k0<<<125, 512, 0, stream>>>(src, dst, cnt, csr);
  kA<<<250, 1024, 0, stream>>>(x, cnt, csr, W1, b1, W2, hsA);
  kB<<<250, 1024, 0, stream>>>(hsA, cnt, csr, b2, W3, hsB);
  kC<<<250, 1024, 0, stream>>>(hsB, cnt, csr, b3, Wd1, partial, done,
                               bd1, Wd2, bd2, Wd3, bd3, Wd4, bd4, out);
}

// Round 7
// 200.267 us; speedup vs baseline: 3.0975x; 1.1025x over previous
//
#include <hip/hip_runtime.h>
#include <math.h>

#define N_NODES 1000
#define E_EDGES 64000
#define STRIDE  256   // padded CSR row stride (max degree ~110 for this graph)

typedef float fx4 __attribute__((ext_vector_type(4)));
typedef float fx2 __attribute__((ext_vector_type(2)));

__device__ inline float lrelu(float v){ return v > 0.f ? v : 0.1f * v; }

// ---- k0: padded-CSR build only
__global__ __launch_bounds__(512)
void k0(const int* __restrict__ src, const int* __restrict__ dst,
        int* __restrict__ cnt, int* __restrict__ csr){
  int e = blockIdx.x * 512 + threadIdx.x;       // 125*512 == 64000 exactly
  int s = src[e], d = dst[e];
  int pos = atomicAdd(&cnt[d], 1);
  if (pos < STRIDE) csr[(d << 8) + pos] = s;
}

// ---- kA: agg(x) [128-wide] -> GEMM1+b1+tanh -> GEMM2 -> hs2 = dinv (.) (h1@W2)
// GEMMs register-tiled: thread = (col-quad cq, k-slice kh); 4 rows x 4 cols/thread.
__global__ __launch_bounds__(1024)
void kA(const float* __restrict__ x, const int* __restrict__ cnt,
        const int* __restrict__ csr, const float* __restrict__ W1,
        const float* __restrict__ b1, const float* __restrict__ W2,
        float* __restrict__ hs2){
  __shared__ float dinv_lds[1024];
  __shared__ fx4 gsum[4][8][32];     // gather partials (16 KB)
  __shared__ float xa[4 * 128];      // aggregated x rows
  __shared__ float h1s[4 * 512];     // tanh layer-1 output (8 KB)
  __shared__ fx4 red[7][4][128];     // k-slice reduce (56 KB)
  int b = blockIdx.x, t = threadIdx.x;
  dinv_lds[t] = (t < N_NODES) ? rsqrtf((float)(cnt[t] + 1)) : 0.f;
  __syncthreads();
  // ---- gather x: node q, 256 thr/node: fx4 col c (32), slice sl (8) ----
  {
    int q = t >> 8, tt = t & 255;
    int c = tt & 31, sl = tt >> 5;
    int n = b * 4 + q;
    int m = cnt[n]; if (m > STRIDE) m = STRIDE;
    const fx4* x4 = (const fx4*)x;
    const int* row = csr + (n << 8);
    fx4 acc = {0.f, 0.f, 0.f, 0.f};
    if (sl == 0) acc = dinv_lds[n] * x4[n * 32 + c];   // self loop
    for (int i = sl; i < m; i += 8){
      int sv = row[i];
      acc += dinv_lds[sv] * x4[sv * 32 + c];
    }
    gsum[q][sl][c] = acc;
    __syncthreads();
    if (sl < 4) gsum[q][sl][c] += gsum[q][sl + 4][c];
    __syncthreads();
    if (sl < 2) gsum[q][sl][c] += gsum[q][sl + 2][c];
    __syncthreads();
    if (sl == 0)
      ((fx4*)xa)[q * 32 + c] = dinv_lds[n] * (gsum[q][0][c] + gsum[q][1][c]);
    __syncthreads();
  }
  int cq = t & 127, kh = t >> 7;
  // ---- GEMM1: [4x128]@[128x512] + b1, tanh -> h1s ----
  {
    fx4 a0 = {0,0,0,0}, a1 = {0,0,0,0}, a2 = {0,0,0,0}, a3 = {0,0,0,0};
    int kb = kh * 16;
    const fx4* Wp = (const fx4*)W1 + (size_t)kb * 128 + cq;
    #pragma unroll
    for (int k = 0; k < 16; ++k){
      fx4 w = Wp[k * 128];
      float h0 = xa[0 * 128 + kb + k], h1 = xa[1 * 128 + kb + k];
      float h2 = xa[2 * 128 + kb + k], h3 = xa[3 * 128 + kb + k];
      a0 += h0 * w; a1 += h1 * w; a2 += h2 * w; a3 += h3 * w;
    }
    if (kh > 0){
      red[kh-1][0][cq] = a0; red[kh-1][1][cq] = a1;
      red[kh-1][2][cq] = a2; red[kh-1][3][cq] = a3;
    }
    __syncthreads();
    if (kh == 0){
      #pragma unroll
      for (int s = 0; s < 7; ++s){
        a0 += red[s][0][cq]; a1 += red[s][1][cq];
        a2 += red[s][2][cq]; a3 += red[s][3][cq];
      }
      fx4 bb = ((const fx4*)b1)[cq];
      fx4* H = (fx4*)h1s;
      fx4 o;
      o.x=tanhf(a0.x+bb.x); o.y=tanhf(a0.y+bb.y); o.z=tanhf(a0.z+bb.z); o.w=tanhf(a0.w+bb.w); H[0*128+cq]=o;
      o.x=tanhf(a1.x+bb.x); o.y=tanhf(a1.y+bb.y); o.z=tanhf(a1.z+bb.z); o.w=tanhf(a1.w+bb.w); H[1*128+cq]=o;
      o.x=tanhf(a2.x+bb.x); o.y=tanhf(a2.y+bb.y); o.z=tanhf(a2.z+bb.z); o.w=tanhf(a2.w+bb.w); H[2*128+cq]=o;
      o.x=tanhf(a3.x+bb.x); o.y=tanhf(a3.y+bb.y); o.z=tanhf(a3.z+bb.z); o.w=tanhf(a3.w+bb.w); H[3*128+cq]=o;
    }
    __syncthreads();
  }
  // ---- GEMM2: [4x512]@[512x512] -> hs2 (pre-scaled by dinv_dst) ----
  {
    fx4 a0 = {0,0,0,0}, a1 = {0,0,0,0}, a2 = {0,0,0,0}, a3 = {0,0,0,0};
    int kb = kh * 64;
    const fx4* Wp = (const fx4*)W2 + (size_t)kb * 128 + cq;
    #pragma unroll 8
    for (int k = 0; k < 64; ++k){
      fx4 w = Wp[k * 128];
      float h0 = h1s[0 * 512 + kb + k], h1 = h1s[1 * 512 + kb + k];
      float h2 = h1s[2 * 512 + kb + k], h3 = h1s[3 * 512 + kb + k];
      a0 += h0 * w; a1 += h1 * w; a2 += h2 * w; a3 += h3 * w;
    }
    if (kh > 0){
      red[kh-1][0][cq] = a0; red[kh-1][1][cq] = a1;
      red[kh-1][2][cq] = a2; red[kh-1][3][cq] = a3;
    }
    __syncthreads();
    if (kh == 0){
      #pragma unroll
      for (int s = 0; s < 7; ++s){
        a0 += red[s][0][cq]; a1 += red[s][1][cq];
        a2 += red[s][2][cq]; a3 += red[s][3][cq];
      }
      int r0 = b * 4;
      fx4* O = (fx4*)hs2;
      O[(size_t)(r0 + 0) * 128 + cq] = a0 * dinv_lds[r0 + 0];
      O[(size_t)(r0 + 1) * 128 + cq] = a1 * dinv_lds[r0 + 1];
      O[(size_t)(r0 + 2) * 128 + cq] = a2 * dinv_lds[r0 + 2];
      O[(size_t)(r0 + 3) * 128 + cq] = a3 * dinv_lds[r0 + 3];
    }
  }
}

// ---- kB: agg(hs_in pre-scaled) + b,tanh -> register-tiled GEMM W3 -> hs_out pre-scaled
__global__ __launch_bounds__(1024)
void kB(const float* __restrict__ hs_in, const int* __restrict__ cnt,
        const int* __restrict__ csr, const float* __restrict__ bias,
        const float* __restrict__ W, float* __restrict__ hs_out){
  __shared__ float h2l[4 * 512];
  __shared__ fx4 hpart[4][128];
  __shared__ fx4 red[7][4][128];
  int b = blockIdx.x, t = threadIdx.x;
  {
    int q = t >> 8, tt = t & 255;
    int c = tt & 127, half = tt >> 7;
    int n = b * 4 + q;
    int m = cnt[n]; if (m > STRIDE) m = STRIDE;
    const fx4* h4 = (const fx4*)hs_in;
    const int* row = csr + (n << 8);
    fx4 s = {0.f, 0.f, 0.f, 0.f};
    if (half == 0) s = h4[n * 128 + c];            // self (pre-scaled)
    int i = half;
    for (; i + 6 < m; i += 8){
      int s0 = row[i], s1 = row[i + 2], s2 = row[i + 4], s3 = row[i + 6];
      s += h4[s0 * 128 + c] + h4[s1 * 128 + c]
         + h4[s2 * 128 + c] + h4[s3 * 128 + c];
    }
    for (; i < m; i += 2) s += h4[row[i] * 128 + c];
    if (half == 1) hpart[q][c] = s;
    __syncthreads();
    if (half == 0){
      s += hpart[q][c];
      float dn = rsqrtf((float)(m + 1));
      fx4 bb = ((const fx4*)bias)[c];
      fx4 o;
      o.x = tanhf(dn * s.x + bb.x);
      o.y = tanhf(dn * s.y + bb.y);
      o.z = tanhf(dn * s.z + bb.z);
      o.w = tanhf(dn * s.w + bb.w);
      ((fx4*)h2l)[q * 128 + c] = o;
    }
    __syncthreads();
  }
  // ---- GEMM: [4x512]@[512x512] register-tiled ----
  int cq = t & 127, kh = t >> 7;
  fx4 a0 = {0,0,0,0}, a1 = {0,0,0,0}, a2 = {0,0,0,0}, a3 = {0,0,0,0};
  int kb = kh * 64;
  const fx4* Wp = (const fx4*)W + (size_t)kb * 128 + cq;
  #pragma unroll 8
  for (int k = 0; k < 64; ++k){
    fx4 w = Wp[k * 128];
    float h0 = h2l[0 * 512 + kb + k], h1 = h2l[1 * 512 + kb + k];
    float h2 = h2l[2 * 512 + kb + k], h3 = h2l[3 * 512 + kb + k];
    a0 += h0 * w; a1 += h1 * w; a2 += h2 * w; a3 += h3 * w;
  }
  if (kh > 0){
    red[kh-1][0][cq] = a0; red[kh-1][1][cq] = a1;
    red[kh-1][2][cq] = a2; red[kh-1][3][cq] = a3;
  }
  __syncthreads();
  if (kh == 0){
    #pragma unroll
    for (int s = 0; s < 7; ++s){
      a0 += red[s][0][cq]; a1 += red[s][1][cq];
      a2 += red[s][2][cq]; a3 += red[s][3][cq];
    }
    int r0 = b * 4;
    fx4* O = (fx4*)hs_out;
    O[(size_t)(r0 + 0) * 128 + cq] = a0 * rsqrtf((float)(cnt[r0 + 0] + 1));
    O[(size_t)(r0 + 1) * 128 + cq] = a1 * rsqrtf((float)(cnt[r0 + 1] + 1));
    O[(size_t)(r0 + 2) * 128 + cq] = a2 * rsqrtf((float)(cnt[r0 + 2] + 1));
    O[(size_t)(r0 + 3) * 128 + cq] = a3 * rsqrtf((float)(cnt[r0 + 3] + 1));
  }
}

// ---- kC: agg layer-3 -> f_lds -> NT-stream Wd1 chunk -> partial; last block tail
__global__ __launch_bounds__(1024)
void kC(const float* __restrict__ hs_in, const int* __restrict__ cnt,
        const int* __restrict__ csr, const float* __restrict__ bias,
        const float* __restrict__ Wd1, float* __restrict__ partial,
        int* __restrict__ done,
        const float* __restrict__ bd1,
        const float* __restrict__ Wd2, const float* __restrict__ bd2,
        const float* __restrict__ Wd3, const float* __restrict__ bd3,
        const float* __restrict__ Wd4, const float* __restrict__ bd4,
        float* __restrict__ out){
  __shared__ float f_lds[2048];
  __shared__ fx4 red4[1024];
  __shared__ float y[256];
  __shared__ int flag;
  int b = blockIdx.x, t = threadIdx.x;
  // warm-touch Wd2/Wd3 into L2/L3 (they get evicted by the Wd1 stream)
  if (b < 8){
    const fx4* w2 = (const fx4*)Wd2;
    const fx4* w3 = (const fx4*)Wd3;
    fx4 v0 = w2[b * 2048 + t] + w3[b * 2048 + t];
    fx4 v1 = w2[b * 2048 + 1024 + t] + w3[b * 2048 + 1024 + t];
    float dm = v0.x + v1.x;
    asm volatile("" :: "v"(dm));
  }
  // ---- agg (inputs pre-scaled by dinv[src]) ----
  int q = t >> 8, tt = t & 255;
  int n = b * 4 + q;
  int m = cnt[n]; if (m > STRIDE) m = STRIDE;
  float dn = rsqrtf((float)(m + 1));
  const fx2* h2 = (const fx2*)hs_in;
  const int* row = csr + (n << 8);
  fx2 s = h2[n * 256 + tt];
  int i = 0;
  for (; i + 4 <= m; i += 4){
    int4 s4 = *(const int4*)(row + i);
    s += h2[s4.x * 256 + tt] + h2[s4.y * 256 + tt]
       + h2[s4.z * 256 + tt] + h2[s4.w * 256 + tt];
  }
  for (; i < m; ++i) s += h2[row[i] * 256 + tt];
  fx2 bb = ((const fx2*)bias)[tt];
  fx2 o;
  o.x = tanhf(dn * s.x + bb.x);
  o.y = tanhf(dn * s.y + bb.y);
  ((fx2*)f_lds)[q * 256 + tt] = o;
  __syncthreads();
  // ---- dense1: NT-stream 2048 rows x 256 cols of Wd1 ----
  int r = t >> 6, c = t & 63;          // 16 rows in flight, 64 fx4 cols
  const fx4* W4 = (const fx4*)Wd1 + (size_t)b * 131072 + c;
  fx4 acc = {0.f, 0.f, 0.f, 0.f};
  #pragma unroll 8
  for (int it = 0; it < 128; ++it){
    int i2 = it * 16 + r;
    acc += f_lds[i2] * __builtin_nontemporal_load(&W4[(size_t)i2 * 64]);
  }
  red4[t] = acc;
  __syncthreads();
  if (t < 512) red4[t] += red4[t + 512];
  __syncthreads();
  if (t < 256) red4[t] += red4[t + 256];
  __syncthreads();
  if (t < 128) red4[t] += red4[t + 128];
  __syncthreads();
  if (t < 64) ((fx4*)(partial + b * 256))[t] = red4[t] + red4[t + 64];
  __syncthreads();
  // ---- last-block-done: only the final block runs the dense tail ----
  if (t == 0){
    __threadfence();
    int old = atomicAdd(done, 1);
    flag = (old == 249);
  }
  __syncthreads();
  if (!flag) return;
  __threadfence();
  float* sm = (float*)red4;
  int c2 = t & 255, h = t >> 8;
  // dense1 reduce + bias + lrelu
  float sum = 0.f;
  for (int bb2 = h; bb2 < 250; bb2 += 4) sum += partial[bb2 * 256 + c2];
  sm[t] = sum;
  __syncthreads();
  if (t < 512) sm[t] += sm[t + 512];
  __syncthreads();
  if (t < 256) y[t] = lrelu(sm[t] + sm[t + 256] + bd1[t]);
  __syncthreads();
  // dense2
  float a = 0.f;
  #pragma unroll 4
  for (int i3 = h * 64; i3 < h * 64 + 64; ++i3) a += y[i3] * Wd2[i3 * 256 + c2];
  sm[t] = a;
  __syncthreads();
  if (t < 512) sm[t] += sm[t + 512];
  __syncthreads();
  if (t < 256) y[t] = lrelu(sm[t] + sm[t + 256] + bd2[t]);
  __syncthreads();
  // dense3
  a = 0.f;
  #pragma unroll 4
  for (int i3 = h * 64; i3 < h * 64 + 64; ++i3) a += y[i3] * Wd3[i3 * 256 + c2];
  sm[t] = a;
  __syncthreads();
  if (t < 512) sm[t] += sm[t + 512];
  __syncthreads();
  if (t < 256) y[t] = lrelu(sm[t] + sm[t + 256] + bd3[t]);
  __syncthreads();
  // dense4
  sm[t] = (t < 256) ? y[t] * Wd4[t] : 0.f;
  __syncthreads();
  for (int off = 128; off > 0; off >>= 1){
    if (t < off) sm[t] += sm[t + off];
    __syncthreads();
  }
  if (t == 0) out[0] = sm[0] + bd4[0];
}

// ---------------- launch ----------------

extern "C" void kernel_launch(void* const* d_in, const int* in_sizes, int n_in,
                              void* d_out, int out_size, void* d_ws, size_t ws_size,
                              hipStream_t stream) {
  const float* x   = (const float*)d_in[0];
  const int*   ei  = (const int*)  d_in[1];
  const float* W1  = (const float*)d_in[2];  const float* b1  = (const float*)d_in[3];
  const float* W2  = (const float*)d_in[4];  const float* b2  = (const float*)d_in[5];
  const float* W3  = (const float*)d_in[6];  const float* b3  = (const float*)d_in[7];
  const float* Wd1 = (const float*)d_in[8];  const float* bd1 = (const float*)d_in[9];
  const float* Wd2 = (const float*)d_in[10]; const float* bd2 = (const float*)d_in[11];
  const float* Wd3 = (const float*)d_in[12]; const float* bd3 = (const float*)d_in[13];
  const float* Wd4 = (const float*)d_in[14]; const float* bd4 = (const float*)d_in[15];
  float* out = (float*)d_out;

  const int* src = ei;
  const int* dst = ei + E_EDGES;

  char* ws = (char*)d_ws;
  int*   cnt     = (int*)  (ws + 0);
  int*   done    = (int*)  (ws + 4096);
  int*   csr     = (int*)  (ws + 8192);                   // 1000*256*4 B
  float* hsA     = (float*)(ws + 1114112);                // 2 MB
  float* hsB     = (float*)(ws + 1114112 + 2097152);      // 2 MB
  float* partial = (float*)(ws + 1114112 + 2 * 2097152);  // 250*256*4

  (void)hipMemsetAsync(ws, 0, 8192, stream);              // cnt + done
  k0<<<125, 512, 0, stream>>>(src, dst, cnt, csr);
  kA<<<250, 1024, 0, stream>>>(x, cnt, csr, W1, b1, W2, hsA);
  kB<<<250, 1024, 0, stream>>>(hsA, cnt, csr, b2, W3, hsB);
  kC<<<250, 1024, 0, stream>>>(hsB, cnt, csr, b3, Wd1, partial, done,
                               bd1, Wd2, bd2, Wd3, bd3, Wd4, bd4, out);
}